// Round 21
// baseline (173.100 us; speedup 1.0000x reference)
//
#include <hip/hip_runtime.h>
#include <hip/hip_bf16.h>

typedef __bf16 bf16;
typedef __bf16 v8bf __attribute__((ext_vector_type(8)));
typedef float f32x4 __attribute__((ext_vector_type(4)));

#define BB 16
#define CCH 128
#define HH 96
#define WW 96
#define EE 6
#define HP 98

#define PPITCH 40      // Patch row pitch in bf16 elems (80 B = 32 data + 16 pad)
#define HPITCH 136     // Ht row pitch in bf16 elems (272 B = 256 data + 16 pad)

static constexpr size_t XP_ELEMS   = (size_t)BB * HP * HP * CCH;
static constexpr size_t WT1R_ELEMS = (size_t)EE * 36 * 4096;
static constexpr size_t WT2R_ELEMS = (size_t)EE * 4 * 4096;
static constexpr size_t XP_BYTES   = XP_ELEMS * 2;
static constexpr size_t WT1R_BYTES = WT1R_ELEMS * 2;
static constexpr size_t WT2R_BYTES = WT2R_ELEMS * 2;

static constexpr int PAD_BLOCKS = HH * BB;                                   // 1536
static constexpr int WT_BLOCKS  = (int)((WT1R_ELEMS + WT2R_ELEMS + 255) / 256); // 874

__device__ inline bf16 to_bf16(float f) { return (bf16)f; }

__device__ __forceinline__ void gload16(const bf16* gsrc, bf16* ldst_wave_uniform) {
    __builtin_amdgcn_global_load_lds(
        (const __attribute__((address_space(1))) unsigned int*)gsrc,
        (__attribute__((address_space(3))) unsigned int*)ldst_wave_uniform, 16, 0, 0);
}

#define WAITVM0 asm volatile("s_waitcnt vmcnt(0)" ::: "memory")

// ---------------- fused pad (+halo, +row sums) and weight transform ----------------
__global__ void padwt_kernel(const float* __restrict__ x, bf16* __restrict__ xp,
                             float* __restrict__ meanpart,
                             const float* __restrict__ w1, const float* __restrict__ w2,
                             bf16* __restrict__ wt1r, bf16* __restrict__ wt2r) {
    const int blk = blockIdx.x;
    const int t = threadIdx.x;
    if (blk >= PAD_BLOCKS) {
        // ---- weight transform path (frag-contiguous layout, verified R10) ----
        const int idx = (blk - PAD_BLOCKS) * 256 + t;
        const int W1N = (int)WT1R_ELEMS;
        if (idx < W1N) {
            int o = idx & 4095;
            int lo = o & 7;
            int l8 = (o >> 3) & 63;
            int rblk = o >> 9;
            int lh2 = l8 >> 4, lr2 = l8 & 15;
            int row = rblk * 16 + lr2;
            int kk = lh2 * 8 + lo;
            int cg = idx >> 12;
            int e = cg / 36, c = cg - e * 36;
            int q = c / 9, tap = c - q * 9;
            int cin = q * 32 + kk;
            wt1r[idx] = to_bf16(w1[((size_t)(e * CCH + row) * CCH + cin) * 9 + tap]);
        } else if (idx < W1N + (int)WT2R_ELEMS) {
            int j2 = idx - W1N;
            int o = j2 & 4095;
            int lo = o & 7;
            int l8 = (o >> 3) & 63;
            int rblk = o >> 9;
            int lh2 = l8 >> 4, lr2 = l8 & 15;
            int row = rblk * 16 + lr2;
            int kk = lh2 * 8 + lo;
            int cg = j2 >> 12;
            int e = cg >> 2, kc = cg & 3;
            int cin = kc * 32 + kk;
            wt2r[j2] = to_bf16(w2[(size_t)(e * CCH + row) * CCH + cin]);
        }
        return;
    }
    // ---- pad path ----
    __shared__ float tile[WW][CCH + 2];
    __shared__ float part[2][CCH];
    const int y = blk % HH;
    const int b = blk / HH;
    const float* src = x + (size_t)b * CCH * HH * WW + (size_t)y * WW;
    bf16* xpb = xp + (size_t)b * HP * HP * CCH;
    for (int i = t; i < CCH * WW; i += 256) {
        int c = i / WW;
        int xx = i - c * WW;
        tile[xx][c] = src[(size_t)c * HH * WW + xx];
    }
    uint4 z; z.x = z.y = z.z = z.w = 0u;
    if (t < 32) {
        int col = t >> 4, gci = t & 15;
        int xx = col ? 97 : 0;
        *reinterpret_cast<uint4*>(xpb + (((size_t)(y + 1)) * HP + xx) * CCH + gci * 8) = z;
    }
    if (y == 0)
        for (int m = t; m < 98 * 16; m += 256) {
            int cell = m >> 4, gci = m & 15;
            *reinterpret_cast<uint4*>(xpb + ((size_t)cell) * CCH + gci * 8) = z;
        }
    if (y == HH - 1)
        for (int m = t; m < 98 * 16; m += 256) {
            int cell = m >> 4, gci = m & 15;
            *reinterpret_cast<uint4*>(xpb + ((size_t)97 * HP + cell) * CCH + gci * 8) = z;
        }
    __syncthreads();
    bf16* dst = xpb + (((size_t)(y + 1)) * HP + 1) * CCH;
    for (int j = t; j < WW * CCH / 2; j += 256) {
        int xx = j >> 6;
        int c2 = (j & 63) * 2;
        bf16 pr[2] = { to_bf16(tile[xx][c2]), to_bf16(tile[xx][c2 + 1]) };
        *reinterpret_cast<uint*>(&dst[(size_t)xx * CCH + c2]) = *reinterpret_cast<uint*>(pr);
    }
    const int c = t & 127, half = t >> 7;
    float s = 0.f;
    for (int xx = half * 48; xx < half * 48 + 48; ++xx) s += tile[xx][c];
    part[half][c] = s;
    __syncthreads();
    if (t < 128) meanpart[((size_t)b * HH + y) * CCH + t] = part[0][t] + part[1][t];
}

// ---------------- fused reduce_mean + router (single block) ----------------
__global__ void router_kernel(const float* __restrict__ meanpart, const float* __restrict__ Wr,
                              const float* __restrict__ br, int* __restrict__ eidx,
                              float* __restrict__ gval, float* __restrict__ total_out) {
    __shared__ float meanbc_s[BB * CCH];      // 8 KB
    __shared__ double logits_s[BB][EE];
    __shared__ double probs[BB][EE];
    const int t = threadIdx.x;
    for (int bc = t; bc < BB * CCH; bc += 256) {
        int b = bc >> 7, c = bc & 127;
        float s = 0.f;
        for (int y = 0; y < HH; ++y) s += meanpart[((size_t)b * HH + y) * CCH + c];
        meanbc_s[bc] = s * (1.f / (HH * WW));
    }
    __syncthreads();
    if (t < BB * EE) {
        const int b = t / EE, e = t - (t / EE) * EE;
        double s = (double)br[e];
        for (int c = 0; c < CCH; ++c)
            s += (double)meanbc_s[b * CCH + c] * (double)Wr[c * EE + e];
        if (s > 10.0) s = 10.0;
        if (s < -10.0) s = -10.0;
        logits_s[b][e] = s;
    }
    __syncthreads();
    if (t < BB) {
        const int b = t;
        double mx = logits_s[b][0];
        for (int e = 1; e < EE; ++e) mx = fmax(mx, logits_s[b][e]);
        double den = 0.0, p[EE];
        for (int e = 0; e < EE; ++e) { p[e] = exp(logits_s[b][e] - mx); den += p[e]; }
        for (int e = 0; e < EE; ++e) {
            p[e] /= den;
            if (p[e] < 1e-6) p[e] = 1e-6;
            if (p[e] > 1.0)  p[e] = 1.0;
            probs[b][e] = p[e];
        }
        int e0 = 0;
        for (int e = 1; e < EE; ++e) if (p[e] > p[e0]) e0 = e;
        int e1 = (e0 == 0) ? 1 : 0;
        for (int e = 0; e < EE; ++e) if (e != e0 && p[e] > p[e1]) e1 = e;
        double s2 = p[e0] + p[e1] + 1e-8;
        eidx[b * 2 + 0] = e0;
        eidx[b * 2 + 1] = e1;
        gval[b * 2 + 0] = (float)(p[e0] / s2);
        gval[b * 2 + 1] = (float)(p[e1] / s2);
    }
    __syncthreads();
    if (t == 0) {
        double usage[EE] = {0, 0, 0, 0, 0, 0};
        double ent = 0.0;
        for (int b = 0; b < BB; ++b) {
            double eb = 0.0;
            for (int e = 0; e < EE; ++e) {
                double pv = probs[b][e];
                usage[e] += pv;
                eb -= pv * log(pv + 1e-10);
            }
            ent += eb;
        }
        ent /= (double)BB;
        double lb = 0.0;
        for (int e = 0; e < EE; ++e) {
            double u = usage[e] / (double)BB - 1.0 / (double)EE;
            lb += u * u;
        }
        *total_out = (float)(lb * 5e-4 - ent * 1e-3);
    }
}

// ---------------- fused MoE conv block (R20 core; epilogue reads xp not x) ----------------
__launch_bounds__(256, 4)
__global__ void moe_conv_kernel(const bf16* __restrict__ xp,
                                const bf16* __restrict__ wt1r, const bf16* __restrict__ wt2r,
                                const float* __restrict__ b1, const float* __restrict__ b2,
                                const int* __restrict__ eidx, const float* __restrict__ gval,
                                float* __restrict__ out) {
    __shared__ __align__(16) bf16 Patch[2][108 * PPITCH];  // 2 x 8640 B
    __shared__ __align__(16) bf16 Ht[64 * HPITCH];         // 17408 B -> 34688 B total

    const int wgid = blockIdx.x;
    const int work = (wgid & 7) * 288 + (wgid >> 3);
    const int b = work / 144;
    const int tile = work - b * 144;
    const int ty = tile / 6, tx = tile - ty * 6;
    const int y0 = ty * 4, x0 = tx * 16;

    const int t = threadIdx.x;
    const int lane = t & 63;
    const int w = t >> 6;
    const int lr = lane & 15;
    const int lh = lane >> 4;
    const int lq = lh * 4;

    const bf16* xpb = xp + (size_t)b * HP * HP * CCH;
    const int e0 = eidx[b * 2 + 0], e1 = eidx[b * 2 + 1];
    const float g0 = gval[b * 2 + 0], g1 = gval[b * 2 + 1];

    auto patch_dma = [&](int qn, int pb2) {
        bf16* base = &Patch[pb2][0];
        #pragma unroll
        for (int it = 0; it < 3; ++it) {
            int m = it * 256 + t;
            if (m < 540) {
                int rp = m / 5, sl = m - rp * 5;
                int g = (sl < 4) ? sl : 3;
                int py = rp / 18, px = rp - py * 18;
                gload16(xpb + ((size_t)(y0 + py) * HP + (x0 + px)) * CCH + qn * 32 + g * 8,
                        base + (it * 256 + w * 64) * 8);
            }
        }
    };
    auto loadA = [&](const bf16* chunk, v8bf* af) {
        #pragma unroll
        for (int i = 0; i < 2; ++i)
            af[i] = *reinterpret_cast<const v8bf*>(chunk + ((w * 2 + i) * 64 + lane) * 8);
    };

    const bf16* pL0 = &Patch[0][lr * PPITCH + lh * 8];
    const bf16* pL1 = &Patch[1][lr * PPITCH + lh * 8];
    const bf16* hL  = &Ht[lr * HPITCH + lh * 8];

    f32x4 accA[2][4], accB[2][4];
    #pragma unroll
    for (int i = 0; i < 2; ++i)
        #pragma unroll
        for (int j = 0; j < 4; ++j) {
            f32x4 z = {0.f, 0.f, 0.f, 0.f};
            accA[i][j] = z; accB[i][j] = z;
        }

    patch_dma(0, 0);
    WAITVM0;
    __builtin_amdgcn_s_barrier();

#define DO_TAP(TAP, AC0, AC1, AN0, AN1)                                        \
    {                                                                          \
        if ((TAP) < 8) {                                                       \
            loadA(wb0 + ((TAP) + 1) * 4096, AN0);                              \
            loadA(wb1 + ((TAP) + 1) * 4096, AN1);                              \
        }                                                                      \
        v8bf bv[4];                                                            \
        const int ry_ = (TAP) / 3, sx_ = (TAP) % 3;                            \
        _Pragma("unroll")                                                      \
        for (int j = 0; j < 4; ++j)                                            \
            bv[j] = *reinterpret_cast<const v8bf*>(&pbL[((j + ry_) * 18 + sx_) * PPITCH]); \
        __builtin_amdgcn_s_setprio(1);                                         \
        _Pragma("unroll")                                                      \
        for (int i = 0; i < 2; ++i) {                                          \
            _Pragma("unroll")                                                  \
            for (int j = 0; j < 4; ++j) {                                      \
                accA[i][j] = __builtin_amdgcn_mfma_f32_16x16x32_bf16(AC0[i], bv[j], accA[i][j], 0, 0, 0); \
                accB[i][j] = __builtin_amdgcn_mfma_f32_16x16x32_bf16(AC1[i], bv[j], accB[i][j], 0, 0, 0); \
            }                                                                  \
        }                                                                      \
        __builtin_amdgcn_s_setprio(0);                                         \
    }

    #pragma unroll 1
    for (int q = 0; q < 4; ++q) {
        const bf16* pbL = (q & 1) ? pL1 : pL0;
        const bf16* wb0 = wt1r + ((size_t)(e0 * 36 + q * 9)) * 4096;
        const bf16* wb1 = wt1r + ((size_t)(e1 * 36 + q * 9)) * 4096;

        v8bf P0[2], P1[2], Q0[2], Q1[2];
        loadA(wb0, P0);
        loadA(wb1, P1);
        if (q < 3) patch_dma(q + 1, (q + 1) & 1);

        DO_TAP(0, P0, P1, Q0, Q1)
        DO_TAP(1, Q0, Q1, P0, P1)
        DO_TAP(2, P0, P1, Q0, Q1)
        DO_TAP(3, Q0, Q1, P0, P1)
        DO_TAP(4, P0, P1, Q0, Q1)
        DO_TAP(5, Q0, Q1, P0, P1)
        DO_TAP(6, P0, P1, Q0, Q1)
        DO_TAP(7, Q0, Q1, P0, P1)
        DO_TAP(8, P0, P1, Q0, Q1)

        if (q < 3) {
            WAITVM0;
            __builtin_amdgcn_s_barrier();
        }
    }
#undef DO_TAP

    #pragma unroll
    for (int ek = 0; ek < 2; ++ek) {
        const int e = ek ? e1 : e0;
        const float g = ek ? g1 : g0;
        const float* b1e = b1 + e * CCH;
        #pragma unroll
        for (int i = 0; i < 2; ++i) {
            const int cb = w * 32 + i * 16 + lq;
            float bias[4];
            #pragma unroll
            for (int q2 = 0; q2 < 4; ++q2) bias[q2] = b1e[cb + q2];
            #pragma unroll
            for (int j = 0; j < 4; ++j) {
                const int pos = j * 16 + lr;
                f32x4 src = ek ? accB[i][j] : accA[i][j];
                if (ek == 0) { f32x4 z = {0.f,0.f,0.f,0.f}; accA[i][j] = z; }
                bf16 hv[4];
                #pragma unroll
                for (int q2 = 0; q2 < 4; ++q2) {
                    float v = src[q2] + bias[q2];
                    float en = __expf(-1.5957691216057308f * v * fmaf(0.044715f, v * v, 1.0f));
                    float s  = __builtin_amdgcn_rcpf(1.0f + en);
                    hv[q2] = to_bf16(g * v * s);
                }
                *reinterpret_cast<uint2*>(&Ht[pos * HPITCH + cb]) =
                    *reinterpret_cast<uint2*>(hv);
            }
        }
        __syncthreads();

        const bf16* w2b = wt2r + (size_t)e * 4 * 4096;
        v8bf afc[2], afn[2];
        loadA(w2b, afc);
        #pragma unroll
        for (int kc = 0; kc < 4; ++kc) {
            if (kc < 3) loadA(w2b + (kc + 1) * 4096, afn);
            v8bf bv[4];
            #pragma unroll
            for (int j = 0; j < 4; ++j)
                bv[j] = *reinterpret_cast<const v8bf*>(&hL[j * 16 * HPITCH + kc * 32]);
            __builtin_amdgcn_s_setprio(1);
            #pragma unroll
            for (int i = 0; i < 2; ++i)
                #pragma unroll
                for (int j = 0; j < 4; ++j)
                    accA[i][j] = __builtin_amdgcn_mfma_f32_16x16x32_bf16(afc[i], bv[j], accA[i][j], 0, 0, 0);
            __builtin_amdgcn_s_setprio(0);
            if (kc < 3) {
                afc[0] = afn[0];
                afc[1] = afn[1];
            }
        }
        if (ek == 0) __syncthreads();
    }

    // ---- epilogue: out = accA + (g0*b2[e0] + g1*b2[e1]) + (g0+g1)*xp  (bf16 x, L3-hot) ----
    const float gsum = g0 + g1;
    #pragma unroll
    for (int i = 0; i < 2; ++i) {
        const int cb = w * 32 + i * 16 + lq;
        float bs[4];
        #pragma unroll
        for (int q2 = 0; q2 < 4; ++q2)
            bs[q2] = g0 * b2[e0 * CCH + cb + q2] + g1 * b2[e1 * CCH + cb + q2];
        #pragma unroll
        for (int j = 0; j < 4; ++j) {
            const int pos = j * 16 + lr;
            const int yy = y0 + (pos >> 4), xx = x0 + (pos & 15);
            // 4 couts in one 8B load from padded xp
            uint2 xr = *reinterpret_cast<const uint2*>(
                xpb + (((size_t)(yy + 1)) * HP + (xx + 1)) * CCH + cb);
            const bf16* xv = reinterpret_cast<const bf16*>(&xr);
            #pragma unroll
            for (int q2 = 0; q2 < 4; ++q2) {
                size_t gi = (((size_t)b * CCH + cb + q2) * HH + yy) * WW + xx;
                out[gi] = accA[i][j][q2] + bs[q2] + gsum * (float)xv[q2];
            }
        }
    }
}

extern "C" void kernel_launch(void* const* d_in, const int* in_sizes, int n_in,
                              void* d_out, int out_size, void* d_ws, size_t ws_size,
                              hipStream_t stream) {
    const float* x  = (const float*)d_in[0];
    const float* Wr = (const float*)d_in[1];
    const float* br = (const float*)d_in[2];
    const float* W1 = (const float*)d_in[3];
    const float* b1 = (const float*)d_in[4];
    const float* W2 = (const float*)d_in[5];
    const float* b2 = (const float*)d_in[6];
    float* out = (float*)d_out;

    char* ws = (char*)d_ws;
    bf16* xp    = (bf16*)ws;
    bf16* wt1r  = (bf16*)(ws + XP_BYTES);
    bf16* wt2r  = (bf16*)(ws + XP_BYTES + WT1R_BYTES);
    float* meanpart = (float*)(ws + XP_BYTES + WT1R_BYTES + WT2R_BYTES);
    int*   eidx     = (int*)(ws + XP_BYTES + WT1R_BYTES + WT2R_BYTES + (size_t)BB * HH * CCH * 4);
    float* gvals    = (float*)(ws + XP_BYTES + WT1R_BYTES + WT2R_BYTES + (size_t)BB * HH * CCH * 4 + BB * 2 * 4);
    float* total    = out + (size_t)BB * CCH * HH * WW;

    padwt_kernel<<<PAD_BLOCKS + WT_BLOCKS, 256, 0, stream>>>(x, xp, meanpart, W1, W2, wt1r, wt2r);
    router_kernel<<<1, 256, 0, stream>>>(meanpart, Wr, br, eidx, gvals, total);
    moe_conv_kernel<<<2304, 256, 0, stream>>>(xp, wt1r, wt2r, b1, b2, eidx, gvals, out);
}

// Round 22
// 159.010 us; speedup vs baseline: 1.0886x; 1.0886x over previous
//
#include <hip/hip_runtime.h>
#include <hip/hip_bf16.h>

typedef __bf16 bf16;
typedef __bf16 v8bf __attribute__((ext_vector_type(8)));
typedef float f32x4 __attribute__((ext_vector_type(4)));

#define BB 16
#define CCH 128
#define HH 96
#define WW 96
#define EE 6
#define HP 98

#define PPITCH 40      // Patch row pitch in bf16 elems (80 B = 32 data + 16 pad)
#define HPITCH 136     // Ht row pitch in bf16 elems (272 B = 256 data + 16 pad)

static constexpr size_t XP_ELEMS   = (size_t)BB * HP * HP * CCH;
static constexpr size_t WT1R_ELEMS = (size_t)EE * 36 * 4096;
static constexpr size_t WT2R_ELEMS = (size_t)EE * 4 * 4096;
static constexpr size_t XP_BYTES   = XP_ELEMS * 2;
static constexpr size_t WT1R_BYTES = WT1R_ELEMS * 2;
static constexpr size_t WT2R_BYTES = WT2R_ELEMS * 2;

__device__ inline bf16 to_bf16(float f) { return (bf16)f; }

__device__ __forceinline__ void gload16(const bf16* gsrc, bf16* ldst_wave_uniform) {
    __builtin_amdgcn_global_load_lds(
        (const __attribute__((address_space(1))) unsigned int*)gsrc,
        (__attribute__((address_space(3))) unsigned int*)ldst_wave_uniform, 16, 0, 0);
}

#define WAITVM0 asm volatile("s_waitcnt vmcnt(0)" ::: "memory")

// ---------------- pad + halo + channel sums (atomicAdd into sumbc) ----------------
__global__ void pad_kernel(const float* __restrict__ x, bf16* __restrict__ xp,
                           float* __restrict__ sumbc) {
    __shared__ float tile[WW][CCH + 2];
    __shared__ float part[2][CCH];
    const int y = blockIdx.x;
    const int b = blockIdx.y;
    const int t = threadIdx.x;
    const float* src = x + (size_t)b * CCH * HH * WW + (size_t)y * WW;
    bf16* xpb = xp + (size_t)b * HP * HP * CCH;
    for (int i = t; i < CCH * WW; i += 256) {
        int c = i / WW;
        int xx = i - c * WW;
        tile[xx][c] = src[(size_t)c * HH * WW + xx];
    }
    uint4 z; z.x = z.y = z.z = z.w = 0u;
    if (t < 32) {
        int col = t >> 4, gci = t & 15;
        int xx = col ? 97 : 0;
        *reinterpret_cast<uint4*>(xpb + (((size_t)(y + 1)) * HP + xx) * CCH + gci * 8) = z;
    }
    if (y == 0)
        for (int m = t; m < 98 * 16; m += 256) {
            int cell = m >> 4, gci = m & 15;
            *reinterpret_cast<uint4*>(xpb + ((size_t)cell) * CCH + gci * 8) = z;
        }
    if (y == HH - 1)
        for (int m = t; m < 98 * 16; m += 256) {
            int cell = m >> 4, gci = m & 15;
            *reinterpret_cast<uint4*>(xpb + ((size_t)97 * HP + cell) * CCH + gci * 8) = z;
        }
    __syncthreads();
    bf16* dst = xpb + (((size_t)(y + 1)) * HP + 1) * CCH;
    for (int j = t; j < WW * CCH / 2; j += 256) {
        int xx = j >> 6;
        int c2 = (j & 63) * 2;
        bf16 pr[2] = { to_bf16(tile[xx][c2]), to_bf16(tile[xx][c2 + 1]) };
        *reinterpret_cast<uint*>(&dst[(size_t)xx * CCH + c2]) = *reinterpret_cast<uint*>(pr);
    }
    const int c = t & 127, half = t >> 7;
    float s = 0.f;
    for (int xx = half * 48; xx < half * 48 + 48; ++xx) s += tile[xx][c];
    part[half][c] = s;
    __syncthreads();
    if (t < 128) atomicAdd(&sumbc[b * CCH + t], part[0][t] + part[1][t]);
}

// ---------------- weight transform: frag-contiguous layout (verified R10) ----------------
__global__ void wt_kernel(const float* __restrict__ w1, const float* __restrict__ w2,
                          bf16* __restrict__ wt1r, bf16* __restrict__ wt2r) {
    const int idx = blockIdx.x * 256 + threadIdx.x;
    const int W1N = (int)WT1R_ELEMS;
    if (idx < W1N) {
        int o = idx & 4095;
        int lo = o & 7;
        int l8 = (o >> 3) & 63;
        int rblk = o >> 9;
        int lh = l8 >> 4, lr = l8 & 15;
        int row = rblk * 16 + lr;
        int kk = lh * 8 + lo;
        int cg = idx >> 12;
        int e = cg / 36, c = cg - e * 36;
        int q = c / 9, tap = c - q * 9;
        int cin = q * 32 + kk;
        wt1r[idx] = to_bf16(w1[((size_t)(e * CCH + row) * CCH + cin) * 9 + tap]);
    } else if (idx < W1N + (int)WT2R_ELEMS) {
        int j2 = idx - W1N;
        int o = j2 & 4095;
        int lo = o & 7;
        int l8 = (o >> 3) & 63;
        int rblk = o >> 9;
        int lh = l8 >> 4, lr = l8 & 15;
        int row = rblk * 16 + lr;
        int kk = lh * 8 + lo;
        int cg = j2 >> 12;
        int e = cg >> 2, kc = cg & 3;
        int cin = kc * 32 + kk;
        wt2r[j2] = to_bf16(w2[(size_t)(e * CCH + row) * CCH + cin]);
    }
}

// ---------------- router: reads 8KB of channel sums (verified f64 semantics) ----------------
__global__ void router_kernel(const float* __restrict__ sumbc, const float* __restrict__ Wr,
                              const float* __restrict__ br, int* __restrict__ eidx,
                              float* __restrict__ gval, float* __restrict__ total_out) {
    __shared__ double logits_s[BB][EE];
    __shared__ double probs[BB][EE];
    const int t = threadIdx.x;
    if (t < BB * EE) {
        const int b = t / EE, e = t - (t / EE) * EE;
        double s = (double)br[e];
        for (int c = 0; c < CCH; ++c)
            s += (double)(sumbc[b * CCH + c] * (1.f / (HH * WW))) * (double)Wr[c * EE + e];
        if (s > 10.0) s = 10.0;
        if (s < -10.0) s = -10.0;
        logits_s[b][e] = s;
    }
    __syncthreads();
    if (t < BB) {
        const int b = t;
        double mx = logits_s[b][0];
        for (int e = 1; e < EE; ++e) mx = fmax(mx, logits_s[b][e]);
        double den = 0.0, p[EE];
        for (int e = 0; e < EE; ++e) { p[e] = exp(logits_s[b][e] - mx); den += p[e]; }
        for (int e = 0; e < EE; ++e) {
            p[e] /= den;
            if (p[e] < 1e-6) p[e] = 1e-6;
            if (p[e] > 1.0)  p[e] = 1.0;
            probs[b][e] = p[e];
        }
        int e0 = 0;
        for (int e = 1; e < EE; ++e) if (p[e] > p[e0]) e0 = e;
        int e1 = (e0 == 0) ? 1 : 0;
        for (int e = 0; e < EE; ++e) if (e != e0 && p[e] > p[e1]) e1 = e;
        double s2 = p[e0] + p[e1] + 1e-8;
        eidx[b * 2 + 0] = e0;
        eidx[b * 2 + 1] = e1;
        gval[b * 2 + 0] = (float)(p[e0] / s2);
        gval[b * 2 + 1] = (float)(p[e1] / s2);
    }
    __syncthreads();
    if (t == 0) {
        double usage[EE] = {0, 0, 0, 0, 0, 0};
        double ent = 0.0;
        for (int b = 0; b < BB; ++b) {
            double eb = 0.0;
            for (int e = 0; e < EE; ++e) {
                double pv = probs[b][e];
                usage[e] += pv;
                eb -= pv * log(pv + 1e-10);
            }
            ent += eb;
        }
        ent /= (double)BB;
        double lb = 0.0;
        for (int e = 0; e < EE; ++e) {
            double u = usage[e] / (double)BB - 1.0 / (double)EE;
            lb += u * u;
        }
        *total_out = (float)(lb * 5e-4 - ent * 1e-3);
    }
}

// ---------------- fused MoE conv block (R20 core, verified 97us) ----------------
__launch_bounds__(256, 4)
__global__ void moe_conv_kernel(const float* __restrict__ x, const bf16* __restrict__ xp,
                                const bf16* __restrict__ wt1r, const bf16* __restrict__ wt2r,
                                const float* __restrict__ b1, const float* __restrict__ b2,
                                const int* __restrict__ eidx, const float* __restrict__ gval,
                                float* __restrict__ out) {
    __shared__ __align__(16) bf16 Patch[2][108 * PPITCH];  // 2 x 8640 B
    __shared__ __align__(16) bf16 Ht[64 * HPITCH];         // 17408 B -> 34688 B total

    const int wgid = blockIdx.x;
    const int work = (wgid & 7) * 288 + (wgid >> 3);
    const int b = work / 144;
    const int tile = work - b * 144;
    const int ty = tile / 6, tx = tile - ty * 6;
    const int y0 = ty * 4, x0 = tx * 16;

    const int t = threadIdx.x;
    const int lane = t & 63;
    const int w = t >> 6;
    const int lr = lane & 15;
    const int lh = lane >> 4;
    const int lq = lh * 4;

    const bf16* xpb = xp + (size_t)b * HP * HP * CCH;
    const int e0 = eidx[b * 2 + 0], e1 = eidx[b * 2 + 1];
    const float g0 = gval[b * 2 + 0], g1 = gval[b * 2 + 1];

    auto patch_dma = [&](int qn, int pb2) {
        bf16* base = &Patch[pb2][0];
        #pragma unroll
        for (int it = 0; it < 3; ++it) {
            int m = it * 256 + t;
            if (m < 540) {
                int rp = m / 5, sl = m - rp * 5;
                int g = (sl < 4) ? sl : 3;
                int py = rp / 18, px = rp - py * 18;
                gload16(xpb + ((size_t)(y0 + py) * HP + (x0 + px)) * CCH + qn * 32 + g * 8,
                        base + (it * 256 + w * 64) * 8);
            }
        }
    };
    auto loadA = [&](const bf16* chunk, v8bf* af) {
        #pragma unroll
        for (int i = 0; i < 2; ++i)
            af[i] = *reinterpret_cast<const v8bf*>(chunk + ((w * 2 + i) * 64 + lane) * 8);
    };

    const bf16* pL0 = &Patch[0][lr * PPITCH + lh * 8];
    const bf16* pL1 = &Patch[1][lr * PPITCH + lh * 8];
    const bf16* hL  = &Ht[lr * HPITCH + lh * 8];

    f32x4 accA[2][4], accB[2][4];
    #pragma unroll
    for (int i = 0; i < 2; ++i)
        #pragma unroll
        for (int j = 0; j < 4; ++j) {
            f32x4 z = {0.f, 0.f, 0.f, 0.f};
            accA[i][j] = z; accB[i][j] = z;
        }

    patch_dma(0, 0);
    WAITVM0;
    __builtin_amdgcn_s_barrier();

#define DO_TAP(TAP, AC0, AC1, AN0, AN1)                                        \
    {                                                                          \
        if ((TAP) < 8) {                                                       \
            loadA(wb0 + ((TAP) + 1) * 4096, AN0);                              \
            loadA(wb1 + ((TAP) + 1) * 4096, AN1);                              \
        }                                                                      \
        v8bf bv[4];                                                            \
        const int ry_ = (TAP) / 3, sx_ = (TAP) % 3;                            \
        _Pragma("unroll")                                                      \
        for (int j = 0; j < 4; ++j)                                            \
            bv[j] = *reinterpret_cast<const v8bf*>(&pbL[((j + ry_) * 18 + sx_) * PPITCH]); \
        __builtin_amdgcn_s_setprio(1);                                         \
        _Pragma("unroll")                                                      \
        for (int i = 0; i < 2; ++i) {                                          \
            _Pragma("unroll")                                                  \
            for (int j = 0; j < 4; ++j) {                                      \
                accA[i][j] = __builtin_amdgcn_mfma_f32_16x16x32_bf16(AC0[i], bv[j], accA[i][j], 0, 0, 0); \
                accB[i][j] = __builtin_amdgcn_mfma_f32_16x16x32_bf16(AC1[i], bv[j], accB[i][j], 0, 0, 0); \
            }                                                                  \
        }                                                                      \
        __builtin_amdgcn_s_setprio(0);                                         \
    }

    #pragma unroll 1
    for (int q = 0; q < 4; ++q) {
        const bf16* pbL = (q & 1) ? pL1 : pL0;
        const bf16* wb0 = wt1r + ((size_t)(e0 * 36 + q * 9)) * 4096;
        const bf16* wb1 = wt1r + ((size_t)(e1 * 36 + q * 9)) * 4096;

        v8bf P0[2], P1[2], Q0[2], Q1[2];
        loadA(wb0, P0);
        loadA(wb1, P1);
        if (q < 3) patch_dma(q + 1, (q + 1) & 1);

        DO_TAP(0, P0, P1, Q0, Q1)
        DO_TAP(1, Q0, Q1, P0, P1)
        DO_TAP(2, P0, P1, Q0, Q1)
        DO_TAP(3, Q0, Q1, P0, P1)
        DO_TAP(4, P0, P1, Q0, Q1)
        DO_TAP(5, Q0, Q1, P0, P1)
        DO_TAP(6, P0, P1, Q0, Q1)
        DO_TAP(7, Q0, Q1, P0, P1)
        DO_TAP(8, P0, P1, Q0, Q1)

        if (q < 3) {
            WAITVM0;
            __builtin_amdgcn_s_barrier();
        }
    }
#undef DO_TAP

    #pragma unroll
    for (int ek = 0; ek < 2; ++ek) {
        const int e = ek ? e1 : e0;
        const float g = ek ? g1 : g0;
        const float* b1e = b1 + e * CCH;
        #pragma unroll
        for (int i = 0; i < 2; ++i) {
            const int cb = w * 32 + i * 16 + lq;
            float bias[4];
            #pragma unroll
            for (int q2 = 0; q2 < 4; ++q2) bias[q2] = b1e[cb + q2];
            #pragma unroll
            for (int j = 0; j < 4; ++j) {
                const int pos = j * 16 + lr;
                f32x4 src = ek ? accB[i][j] : accA[i][j];
                if (ek == 0) { f32x4 z = {0.f,0.f,0.f,0.f}; accA[i][j] = z; }
                bf16 hv[4];
                #pragma unroll
                for (int q2 = 0; q2 < 4; ++q2) {
                    float v = src[q2] + bias[q2];
                    float en = __expf(-1.5957691216057308f * v * fmaf(0.044715f, v * v, 1.0f));
                    float s  = __builtin_amdgcn_rcpf(1.0f + en);
                    hv[q2] = to_bf16(g * v * s);
                }
                *reinterpret_cast<uint2*>(&Ht[pos * HPITCH + cb]) =
                    *reinterpret_cast<uint2*>(hv);
            }
        }
        __syncthreads();

        const bf16* w2b = wt2r + (size_t)e * 4 * 4096;
        v8bf afc[2], afn[2];
        loadA(w2b, afc);
        #pragma unroll
        for (int kc = 0; kc < 4; ++kc) {
            if (kc < 3) loadA(w2b + (kc + 1) * 4096, afn);
            v8bf bv[4];
            #pragma unroll
            for (int j = 0; j < 4; ++j)
                bv[j] = *reinterpret_cast<const v8bf*>(&hL[j * 16 * HPITCH + kc * 32]);
            __builtin_amdgcn_s_setprio(1);
            #pragma unroll
            for (int i = 0; i < 2; ++i)
                #pragma unroll
                for (int j = 0; j < 4; ++j)
                    accA[i][j] = __builtin_amdgcn_mfma_f32_16x16x32_bf16(afc[i], bv[j], accA[i][j], 0, 0, 0);
            __builtin_amdgcn_s_setprio(0);
            if (kc < 3) {
                afc[0] = afn[0];
                afc[1] = afn[1];
            }
        }
        if (ek == 0) __syncthreads();
    }

    // ---- epilogue: out = accA + (g0*b2[e0] + g1*b2[e1]) + (g0+g1)*x ----
    const float gsum = g0 + g1;
    #pragma unroll
    for (int i = 0; i < 2; ++i) {
        const int cb = w * 32 + i * 16 + lq;
        float bs[4];
        #pragma unroll
        for (int q2 = 0; q2 < 4; ++q2)
            bs[q2] = g0 * b2[e0 * CCH + cb + q2] + g1 * b2[e1 * CCH + cb + q2];
        #pragma unroll
        for (int j = 0; j < 4; ++j) {
            const int pos = j * 16 + lr;
            const int yy = y0 + (pos >> 4), xx = x0 + (pos & 15);
            #pragma unroll
            for (int q2 = 0; q2 < 4; ++q2) {
                size_t gi = (((size_t)b * CCH + cb + q2) * HH + yy) * WW + xx;
                out[gi] = accA[i][j][q2] + bs[q2] + gsum * x[gi];
            }
        }
    }
}

extern "C" void kernel_launch(void* const* d_in, const int* in_sizes, int n_in,
                              void* d_out, int out_size, void* d_ws, size_t ws_size,
                              hipStream_t stream) {
    const float* x  = (const float*)d_in[0];
    const float* Wr = (const float*)d_in[1];
    const float* br = (const float*)d_in[2];
    const float* W1 = (const float*)d_in[3];
    const float* b1 = (const float*)d_in[4];
    const float* W2 = (const float*)d_in[5];
    const float* b2 = (const float*)d_in[6];
    float* out = (float*)d_out;

    char* ws = (char*)d_ws;
    bf16* xp    = (bf16*)ws;
    bf16* wt1r  = (bf16*)(ws + XP_BYTES);
    bf16* wt2r  = (bf16*)(ws + XP_BYTES + WT1R_BYTES);
    float* sumbc = (float*)(ws + XP_BYTES + WT1R_BYTES + WT2R_BYTES);
    int*   eidx  = (int*)(ws + XP_BYTES + WT1R_BYTES + WT2R_BYTES + (size_t)BB * CCH * 4);
    float* gvals = (float*)(ws + XP_BYTES + WT1R_BYTES + WT2R_BYTES + (size_t)BB * CCH * 4 + BB * 2 * 4);
    float* total = out + (size_t)BB * CCH * HH * WW;

    hipMemsetAsync(sumbc, 0, (size_t)BB * CCH * 4, stream);
    pad_kernel<<<dim3(HH, BB), 256, 0, stream>>>(x, xp, sumbc);
    wt_kernel<<<(unsigned)((WT1R_ELEMS + WT2R_ELEMS + 255) / 256), 256, 0, stream>>>(W1, W2, wt1r, wt2r);
    router_kernel<<<1, 128, 0, stream>>>(sumbc, Wr, br, eidx, gvals, total);
    moe_conv_kernel<<<2304, 256, 0, stream>>>(x, xp, wt1r, wt2r, b1, b2, eidx, gvals, out);
}

// Round 23
// 153.156 us; speedup vs baseline: 1.1302x; 1.0382x over previous
//
#include <hip/hip_runtime.h>
#include <hip/hip_bf16.h>

typedef __bf16 bf16;
typedef __bf16 v8bf __attribute__((ext_vector_type(8)));
typedef float f32x4 __attribute__((ext_vector_type(4)));

#define BB 16
#define CCH 128
#define HH 96
#define WW 96
#define EE 6
#define HP 98

#define PPITCH 40      // Patch row pitch in bf16 elems (80 B = 32 data + 16 pad)
#define HPITCH 136     // Ht row pitch in bf16 elems (272 B = 256 data + 16 pad)

static constexpr size_t XP_ELEMS   = (size_t)BB * HP * HP * CCH;
static constexpr size_t WT1R_ELEMS = (size_t)EE * 36 * 4096;
static constexpr size_t WT2R_ELEMS = (size_t)EE * 4 * 4096;
static constexpr size_t XP_BYTES   = XP_ELEMS * 2;
static constexpr size_t WT1R_BYTES = WT1R_ELEMS * 2;
static constexpr size_t WT2R_BYTES = WT2R_ELEMS * 2;

__device__ inline bf16 to_bf16(float f) { return (bf16)f; }

__device__ __forceinline__ void gload16(const bf16* gsrc, bf16* ldst_wave_uniform) {
    __builtin_amdgcn_global_load_lds(
        (const __attribute__((address_space(1))) unsigned int*)gsrc,
        (__attribute__((address_space(3))) unsigned int*)ldst_wave_uniform, 16, 0, 0);
}

#define WAITVM0 asm volatile("s_waitcnt vmcnt(0)" ::: "memory")

// ---------------- weight transform (frag-contiguous, verified R10) + sumbc zeroing ----------------
__global__ void wt_kernel(const float* __restrict__ w1, const float* __restrict__ w2,
                          bf16* __restrict__ wt1r, bf16* __restrict__ wt2r,
                          float* __restrict__ sumbc) {
    if (blockIdx.x == 0) {              // zero the 2048-float channel-sum buffer (runs before pad)
        for (int k = threadIdx.x; k < BB * CCH; k += 256) sumbc[k] = 0.f;
    }
    const int idx = blockIdx.x * 256 + threadIdx.x;
    const int W1N = (int)WT1R_ELEMS;
    if (idx < W1N) {
        int o = idx & 4095;
        int lo = o & 7;
        int l8 = (o >> 3) & 63;
        int rblk = o >> 9;
        int lh = l8 >> 4, lr = l8 & 15;
        int row = rblk * 16 + lr;
        int kk = lh * 8 + lo;
        int cg = idx >> 12;
        int e = cg / 36, c = cg - e * 36;
        int q = c / 9, tap = c - q * 9;
        int cin = q * 32 + kk;
        wt1r[idx] = to_bf16(w1[((size_t)(e * CCH + row) * CCH + cin) * 9 + tap]);
    } else if (idx < W1N + (int)WT2R_ELEMS) {
        int j2 = idx - W1N;
        int o = j2 & 4095;
        int lo = o & 7;
        int l8 = (o >> 3) & 63;
        int rblk = o >> 9;
        int lh = l8 >> 4, lr = l8 & 15;
        int row = rblk * 16 + lr;
        int kk = lh * 8 + lo;
        int cg = j2 >> 12;
        int e = cg >> 2, kc = cg & 3;
        int cin = kc * 32 + kk;
        wt2r[j2] = to_bf16(w2[(size_t)(e * CCH + row) * CCH + cin]);
    }
}

// ---------------- pad + halo + channel sums (vectorized: float4 in, uint4 out) ----------------
__global__ void pad_kernel(const float* __restrict__ x, bf16* __restrict__ xp,
                           float* __restrict__ sumbc) {
    __shared__ float tile[WW][CCH + 2];
    __shared__ float part[2][CCH];
    const int y = blockIdx.x;
    const int b = blockIdx.y;
    const int t = threadIdx.x;
    const float* src = x + (size_t)b * CCH * HH * WW + (size_t)y * WW;
    bf16* xpb = xp + (size_t)b * HP * HP * CCH;
    // read: 128 channels x 24 float4 = 3072 vec loads (16B/lane, coalesced)
    for (int i = t; i < CCH * (WW / 4); i += 256) {
        int c = i / (WW / 4);
        int xq = i - c * (WW / 4);
        float4 v = *reinterpret_cast<const float4*>(src + (size_t)c * HH * WW + xq * 4);
        tile[xq * 4 + 0][c] = v.x;
        tile[xq * 4 + 1][c] = v.y;
        tile[xq * 4 + 2][c] = v.z;
        tile[xq * 4 + 3][c] = v.w;
    }
    // halo zeroing
    uint4 z; z.x = z.y = z.z = z.w = 0u;
    if (t < 32) {
        int col = t >> 4, gci = t & 15;
        int xx = col ? 97 : 0;
        *reinterpret_cast<uint4*>(xpb + (((size_t)(y + 1)) * HP + xx) * CCH + gci * 8) = z;
    }
    if (y == 0)
        for (int m = t; m < 98 * 16; m += 256) {
            int cell = m >> 4, gci = m & 15;
            *reinterpret_cast<uint4*>(xpb + ((size_t)cell) * CCH + gci * 8) = z;
        }
    if (y == HH - 1)
        for (int m = t; m < 98 * 16; m += 256) {
            int cell = m >> 4, gci = m & 15;
            *reinterpret_cast<uint4*>(xpb + ((size_t)97 * HP + cell) * CCH + gci * 8) = z;
        }
    __syncthreads();
    // write: 96 x-positions x 16 groups of 8 bf16 = 1536 uint4 stores (16B/lane)
    bf16* dst = xpb + (((size_t)(y + 1)) * HP + 1) * CCH;
    for (int j = t; j < WW * 16; j += 256) {
        int xx = j >> 4;
        int c8 = (j & 15) * 8;
        bf16 pr[8];
        #pragma unroll
        for (int k = 0; k < 8; ++k) pr[k] = to_bf16(tile[xx][c8 + k]);
        *reinterpret_cast<uint4*>(&dst[(size_t)xx * CCH + c8]) = *reinterpret_cast<uint4*>(pr);
    }
    const int c = t & 127, half = t >> 7;
    float s = 0.f;
    for (int xx = half * 48; xx < half * 48 + 48; ++xx) s += tile[xx][c];
    part[half][c] = s;
    __syncthreads();
    if (t < 128) atomicAdd(&sumbc[b * CCH + t], part[0][t] + part[1][t]);
}

// ---------------- router: reads 8KB of channel sums (verified f64 semantics) ----------------
__global__ void router_kernel(const float* __restrict__ sumbc, const float* __restrict__ Wr,
                              const float* __restrict__ br, int* __restrict__ eidx,
                              float* __restrict__ gval, float* __restrict__ total_out) {
    __shared__ double logits_s[BB][EE];
    __shared__ double probs[BB][EE];
    const int t = threadIdx.x;
    if (t < BB * EE) {
        const int b = t / EE, e = t - (t / EE) * EE;
        double s = (double)br[e];
        for (int c = 0; c < CCH; ++c)
            s += (double)(sumbc[b * CCH + c] * (1.f / (HH * WW))) * (double)Wr[c * EE + e];
        if (s > 10.0) s = 10.0;
        if (s < -10.0) s = -10.0;
        logits_s[b][e] = s;
    }
    __syncthreads();
    if (t < BB) {
        const int b = t;
        double mx = logits_s[b][0];
        for (int e = 1; e < EE; ++e) mx = fmax(mx, logits_s[b][e]);
        double den = 0.0, p[EE];
        for (int e = 0; e < EE; ++e) { p[e] = exp(logits_s[b][e] - mx); den += p[e]; }
        for (int e = 0; e < EE; ++e) {
            p[e] /= den;
            if (p[e] < 1e-6) p[e] = 1e-6;
            if (p[e] > 1.0)  p[e] = 1.0;
            probs[b][e] = p[e];
        }
        int e0 = 0;
        for (int e = 1; e < EE; ++e) if (p[e] > p[e0]) e0 = e;
        int e1 = (e0 == 0) ? 1 : 0;
        for (int e = 0; e < EE; ++e) if (e != e0 && p[e] > p[e1]) e1 = e;
        double s2 = p[e0] + p[e1] + 1e-8;
        eidx[b * 2 + 0] = e0;
        eidx[b * 2 + 1] = e1;
        gval[b * 2 + 0] = (float)(p[e0] / s2);
        gval[b * 2 + 1] = (float)(p[e1] / s2);
    }
    __syncthreads();
    if (t == 0) {
        double usage[EE] = {0, 0, 0, 0, 0, 0};
        double ent = 0.0;
        for (int b = 0; b < BB; ++b) {
            double eb = 0.0;
            for (int e = 0; e < EE; ++e) {
                double pv = probs[b][e];
                usage[e] += pv;
                eb -= pv * log(pv + 1e-10);
            }
            ent += eb;
        }
        ent /= (double)BB;
        double lb = 0.0;
        for (int e = 0; e < EE; ++e) {
            double u = usage[e] / (double)BB - 1.0 / (double)EE;
            lb += u * u;
        }
        *total_out = (float)(lb * 5e-4 - ent * 1e-3);
    }
}

// ---------------- fused MoE conv block (R20/R22 core, verified 96-97us) ----------------
__launch_bounds__(256, 4)
__global__ void moe_conv_kernel(const float* __restrict__ x, const bf16* __restrict__ xp,
                                const bf16* __restrict__ wt1r, const bf16* __restrict__ wt2r,
                                const float* __restrict__ b1, const float* __restrict__ b2,
                                const int* __restrict__ eidx, const float* __restrict__ gval,
                                float* __restrict__ out) {
    __shared__ __align__(16) bf16 Patch[2][108 * PPITCH];  // 2 x 8640 B
    __shared__ __align__(16) bf16 Ht[64 * HPITCH];         // 17408 B -> 34688 B total

    const int wgid = blockIdx.x;
    const int work = (wgid & 7) * 288 + (wgid >> 3);
    const int b = work / 144;
    const int tile = work - b * 144;
    const int ty = tile / 6, tx = tile - ty * 6;
    const int y0 = ty * 4, x0 = tx * 16;

    const int t = threadIdx.x;
    const int lane = t & 63;
    const int w = t >> 6;
    const int lr = lane & 15;
    const int lh = lane >> 4;
    const int lq = lh * 4;

    const bf16* xpb = xp + (size_t)b * HP * HP * CCH;
    const int e0 = eidx[b * 2 + 0], e1 = eidx[b * 2 + 1];
    const float g0 = gval[b * 2 + 0], g1 = gval[b * 2 + 1];

    auto patch_dma = [&](int qn, int pb2) {
        bf16* base = &Patch[pb2][0];
        #pragma unroll
        for (int it = 0; it < 3; ++it) {
            int m = it * 256 + t;
            if (m < 540) {
                int rp = m / 5, sl = m - rp * 5;
                int g = (sl < 4) ? sl : 3;
                int py = rp / 18, px = rp - py * 18;
                gload16(xpb + ((size_t)(y0 + py) * HP + (x0 + px)) * CCH + qn * 32 + g * 8,
                        base + (it * 256 + w * 64) * 8);
            }
        }
    };
    auto loadA = [&](const bf16* chunk, v8bf* af) {
        #pragma unroll
        for (int i = 0; i < 2; ++i)
            af[i] = *reinterpret_cast<const v8bf*>(chunk + ((w * 2 + i) * 64 + lane) * 8);
    };

    const bf16* pL0 = &Patch[0][lr * PPITCH + lh * 8];
    const bf16* pL1 = &Patch[1][lr * PPITCH + lh * 8];
    const bf16* hL  = &Ht[lr * HPITCH + lh * 8];

    f32x4 accA[2][4], accB[2][4];
    #pragma unroll
    for (int i = 0; i < 2; ++i)
        #pragma unroll
        for (int j = 0; j < 4; ++j) {
            f32x4 z = {0.f, 0.f, 0.f, 0.f};
            accA[i][j] = z; accB[i][j] = z;
        }

    patch_dma(0, 0);
    WAITVM0;
    __builtin_amdgcn_s_barrier();

#define DO_TAP(TAP, AC0, AC1, AN0, AN1)                                        \
    {                                                                          \
        if ((TAP) < 8) {                                                       \
            loadA(wb0 + ((TAP) + 1) * 4096, AN0);                              \
            loadA(wb1 + ((TAP) + 1) * 4096, AN1);                              \
        }                                                                      \
        v8bf bv[4];                                                            \
        const int ry_ = (TAP) / 3, sx_ = (TAP) % 3;                            \
        _Pragma("unroll")                                                      \
        for (int j = 0; j < 4; ++j)                                            \
            bv[j] = *reinterpret_cast<const v8bf*>(&pbL[((j + ry_) * 18 + sx_) * PPITCH]); \
        __builtin_amdgcn_s_setprio(1);                                         \
        _Pragma("unroll")                                                      \
        for (int i = 0; i < 2; ++i) {                                          \
            _Pragma("unroll")                                                  \
            for (int j = 0; j < 4; ++j) {                                      \
                accA[i][j] = __builtin_amdgcn_mfma_f32_16x16x32_bf16(AC0[i], bv[j], accA[i][j], 0, 0, 0); \
                accB[i][j] = __builtin_amdgcn_mfma_f32_16x16x32_bf16(AC1[i], bv[j], accB[i][j], 0, 0, 0); \
            }                                                                  \
        }                                                                      \
        __builtin_amdgcn_s_setprio(0);                                         \
    }

    #pragma unroll 1
    for (int q = 0; q < 4; ++q) {
        const bf16* pbL = (q & 1) ? pL1 : pL0;
        const bf16* wb0 = wt1r + ((size_t)(e0 * 36 + q * 9)) * 4096;
        const bf16* wb1 = wt1r + ((size_t)(e1 * 36 + q * 9)) * 4096;

        v8bf P0[2], P1[2], Q0[2], Q1[2];
        loadA(wb0, P0);
        loadA(wb1, P1);
        if (q < 3) patch_dma(q + 1, (q + 1) & 1);

        DO_TAP(0, P0, P1, Q0, Q1)
        DO_TAP(1, Q0, Q1, P0, P1)
        DO_TAP(2, P0, P1, Q0, Q1)
        DO_TAP(3, Q0, Q1, P0, P1)
        DO_TAP(4, P0, P1, Q0, Q1)
        DO_TAP(5, Q0, Q1, P0, P1)
        DO_TAP(6, P0, P1, Q0, Q1)
        DO_TAP(7, Q0, Q1, P0, P1)
        DO_TAP(8, P0, P1, Q0, Q1)

        if (q < 3) {
            WAITVM0;
            __builtin_amdgcn_s_barrier();
        }
    }
#undef DO_TAP

    #pragma unroll
    for (int ek = 0; ek < 2; ++ek) {
        const int e = ek ? e1 : e0;
        const float g = ek ? g1 : g0;
        const float* b1e = b1 + e * CCH;
        #pragma unroll
        for (int i = 0; i < 2; ++i) {
            const int cb = w * 32 + i * 16 + lq;
            float bias[4];
            #pragma unroll
            for (int q2 = 0; q2 < 4; ++q2) bias[q2] = b1e[cb + q2];
            #pragma unroll
            for (int j = 0; j < 4; ++j) {
                const int pos = j * 16 + lr;
                f32x4 src = ek ? accB[i][j] : accA[i][j];
                if (ek == 0) { f32x4 z = {0.f,0.f,0.f,0.f}; accA[i][j] = z; }
                bf16 hv[4];
                #pragma unroll
                for (int q2 = 0; q2 < 4; ++q2) {
                    float v = src[q2] + bias[q2];
                    float en = __expf(-1.5957691216057308f * v * fmaf(0.044715f, v * v, 1.0f));
                    float s  = __builtin_amdgcn_rcpf(1.0f + en);
                    hv[q2] = to_bf16(g * v * s);
                }
                *reinterpret_cast<uint2*>(&Ht[pos * HPITCH + cb]) =
                    *reinterpret_cast<uint2*>(hv);
            }
        }
        __syncthreads();

        const bf16* w2b = wt2r + (size_t)e * 4 * 4096;
        v8bf afc[2], afn[2];
        loadA(w2b, afc);
        #pragma unroll
        for (int kc = 0; kc < 4; ++kc) {
            if (kc < 3) loadA(w2b + (kc + 1) * 4096, afn);
            v8bf bv[4];
            #pragma unroll
            for (int j = 0; j < 4; ++j)
                bv[j] = *reinterpret_cast<const v8bf*>(&hL[j * 16 * HPITCH + kc * 32]);
            __builtin_amdgcn_s_setprio(1);
            #pragma unroll
            for (int i = 0; i < 2; ++i)
                #pragma unroll
                for (int j = 0; j < 4; ++j)
                    accA[i][j] = __builtin_amdgcn_mfma_f32_16x16x32_bf16(afc[i], bv[j], accA[i][j], 0, 0, 0);
            __builtin_amdgcn_s_setprio(0);
            if (kc < 3) {
                afc[0] = afn[0];
                afc[1] = afn[1];
            }
        }
        if (ek == 0) __syncthreads();
    }

    // ---- epilogue: out = accA + (g0*b2[e0] + g1*b2[e1]) + (g0+g1)*x ----
    const float gsum = g0 + g1;
    #pragma unroll
    for (int i = 0; i < 2; ++i) {
        const int cb = w * 32 + i * 16 + lq;
        float bs[4];
        #pragma unroll
        for (int q2 = 0; q2 < 4; ++q2)
            bs[q2] = g0 * b2[e0 * CCH + cb + q2] + g1 * b2[e1 * CCH + cb + q2];
        #pragma unroll
        for (int j = 0; j < 4; ++j) {
            const int pos = j * 16 + lr;
            const int yy = y0 + (pos >> 4), xx = x0 + (pos & 15);
            #pragma unroll
            for (int q2 = 0; q2 < 4; ++q2) {
                size_t gi = (((size_t)b * CCH + cb + q2) * HH + yy) * WW + xx;
                out[gi] = accA[i][j][q2] + bs[q2] + gsum * x[gi];
            }
        }
    }
}

extern "C" void kernel_launch(void* const* d_in, const int* in_sizes, int n_in,
                              void* d_out, int out_size, void* d_ws, size_t ws_size,
                              hipStream_t stream) {
    const float* x  = (const float*)d_in[0];
    const float* Wr = (const float*)d_in[1];
    const float* br = (const float*)d_in[2];
    const float* W1 = (const float*)d_in[3];
    const float* b1 = (const float*)d_in[4];
    const float* W2 = (const float*)d_in[5];
    const float* b2 = (const float*)d_in[6];
    float* out = (float*)d_out;

    char* ws = (char*)d_ws;
    bf16* xp    = (bf16*)ws;
    bf16* wt1r  = (bf16*)(ws + XP_BYTES);
    bf16* wt2r  = (bf16*)(ws + XP_BYTES + WT1R_BYTES);
    float* sumbc = (float*)(ws + XP_BYTES + WT1R_BYTES + WT2R_BYTES);
    int*   eidx  = (int*)(ws + XP_BYTES + WT1R_BYTES + WT2R_BYTES + (size_t)BB * CCH * 4);
    float* gvals = (float*)(ws + XP_BYTES + WT1R_BYTES + WT2R_BYTES + (size_t)BB * CCH * 4 + BB * 2 * 4);
    float* total = out + (size_t)BB * CCH * HH * WW;

    wt_kernel<<<(unsigned)((WT1R_ELEMS + WT2R_ELEMS + 255) / 256), 256, 0, stream>>>(W1, W2, wt1r, wt2r, sumbc);
    pad_kernel<<<dim3(HH, BB), 256, 0, stream>>>(x, xp, sumbc);
    router_kernel<<<1, 128, 0, stream>>>(sumbc, Wr, br, eidx, gvals, total);
    moe_conv_kernel<<<2304, 256, 0, stream>>>(x, xp, wt1r, wt2r, b1, b2, eidx, gvals, out);
}

// Round 24
// 140.245 us; speedup vs baseline: 1.2343x; 1.0921x over previous
//
#include <hip/hip_runtime.h>
#include <hip/hip_bf16.h>

typedef __bf16 bf16;
typedef __bf16 v8bf __attribute__((ext_vector_type(8)));
typedef float f32x4 __attribute__((ext_vector_type(4)));

#define BB 16
#define CCH 128
#define HH 96
#define WW 96
#define EE 6
#define HP 98

#define PPITCH 40      // Patch row pitch in bf16 elems (80 B = 32 data + 16 pad)
#define HPITCH 136     // Ht row pitch in bf16 elems (272 B = 256 data + 16 pad)

static constexpr size_t XP_ELEMS   = (size_t)BB * HP * HP * CCH;
static constexpr size_t WT1R_ELEMS = (size_t)EE * 36 * 4096;
static constexpr size_t WT2R_ELEMS = (size_t)EE * 4 * 4096;
static constexpr size_t XP_BYTES   = XP_ELEMS * 2;
static constexpr size_t WT1R_BYTES = WT1R_ELEMS * 2;
static constexpr size_t WT2R_BYTES = WT2R_ELEMS * 2;

static constexpr int PAD_BLOCKS = HH * BB;                                      // 1536
static constexpr int WT_BLOCKS  = (int)((WT1R_ELEMS + WT2R_ELEMS + 255) / 256); // 874

__device__ inline bf16 to_bf16(float f) { return (bf16)f; }

__device__ __forceinline__ void gload16(const bf16* gsrc, bf16* ldst_wave_uniform) {
    __builtin_amdgcn_global_load_lds(
        (const __attribute__((address_space(1))) unsigned int*)gsrc,
        (__attribute__((address_space(3))) unsigned int*)ldst_wave_uniform, 16, 0, 0);
}

#define WAITVM0 asm volatile("s_waitcnt vmcnt(0)" ::: "memory")

// ---------------- fused: pad (+halo, +channel sums) | weight transform ----------------
__global__ void padwt_kernel(const float* __restrict__ x, bf16* __restrict__ xp,
                             float* __restrict__ sumbc,
                             const float* __restrict__ w1, const float* __restrict__ w2,
                             bf16* __restrict__ wt1r, bf16* __restrict__ wt2r) {
    const int blk = blockIdx.x;
    const int t = threadIdx.x;
    if (blk >= PAD_BLOCKS) {
        // ---- weight transform path (frag-contiguous, verified R10) ----
        const int idx = (blk - PAD_BLOCKS) * 256 + t;
        const int W1N = (int)WT1R_ELEMS;
        if (idx < W1N) {
            int o = idx & 4095;
            int lo = o & 7;
            int l8 = (o >> 3) & 63;
            int rblk = o >> 9;
            int lh2 = l8 >> 4, lr2 = l8 & 15;
            int row = rblk * 16 + lr2;
            int kk = lh2 * 8 + lo;
            int cg = idx >> 12;
            int e = cg / 36, c = cg - e * 36;
            int q = c / 9, tap = c - q * 9;
            int cin = q * 32 + kk;
            wt1r[idx] = to_bf16(w1[((size_t)(e * CCH + row) * CCH + cin) * 9 + tap]);
        } else if (idx < W1N + (int)WT2R_ELEMS) {
            int j2 = idx - W1N;
            int o = j2 & 4095;
            int lo = o & 7;
            int l8 = (o >> 3) & 63;
            int rblk = o >> 9;
            int lh2 = l8 >> 4, lr2 = l8 & 15;
            int row = rblk * 16 + lr2;
            int kk = lh2 * 8 + lo;
            int cg = j2 >> 12;
            int e = cg >> 2, kc = cg & 3;
            int cin = kc * 32 + kk;
            wt2r[j2] = to_bf16(w2[(size_t)(e * CCH + row) * CCH + cin]);
        }
        return;
    }
    // ---- pad path (R23 vectorized body) ----
    __shared__ float tile[WW][CCH + 2];
    __shared__ float part[2][CCH];
    const int y = blk % HH;
    const int b = blk / HH;
    const float* src = x + (size_t)b * CCH * HH * WW + (size_t)y * WW;
    bf16* xpb = xp + (size_t)b * HP * HP * CCH;
    for (int i = t; i < CCH * (WW / 4); i += 256) {
        int c = i / (WW / 4);
        int xq = i - c * (WW / 4);
        float4 v = *reinterpret_cast<const float4*>(src + (size_t)c * HH * WW + xq * 4);
        tile[xq * 4 + 0][c] = v.x;
        tile[xq * 4 + 1][c] = v.y;
        tile[xq * 4 + 2][c] = v.z;
        tile[xq * 4 + 3][c] = v.w;
    }
    uint4 z; z.x = z.y = z.z = z.w = 0u;
    if (t < 32) {
        int col = t >> 4, gci = t & 15;
        int xx = col ? 97 : 0;
        *reinterpret_cast<uint4*>(xpb + (((size_t)(y + 1)) * HP + xx) * CCH + gci * 8) = z;
    }
    if (y == 0)
        for (int m = t; m < 98 * 16; m += 256) {
            int cell = m >> 4, gci = m & 15;
            *reinterpret_cast<uint4*>(xpb + ((size_t)cell) * CCH + gci * 8) = z;
        }
    if (y == HH - 1)
        for (int m = t; m < 98 * 16; m += 256) {
            int cell = m >> 4, gci = m & 15;
            *reinterpret_cast<uint4*>(xpb + ((size_t)97 * HP + cell) * CCH + gci * 8) = z;
        }
    __syncthreads();
    bf16* dst = xpb + (((size_t)(y + 1)) * HP + 1) * CCH;
    for (int j = t; j < WW * 16; j += 256) {
        int xx = j >> 4;
        int c8 = (j & 15) * 8;
        bf16 pr[8];
        #pragma unroll
        for (int k = 0; k < 8; ++k) pr[k] = to_bf16(tile[xx][c8 + k]);
        *reinterpret_cast<uint4*>(&dst[(size_t)xx * CCH + c8]) = *reinterpret_cast<uint4*>(pr);
    }
    const int c = t & 127, half = t >> 7;
    float s = 0.f;
    for (int xx = half * 48; xx < half * 48 + 48; ++xx) s += tile[xx][c];
    part[half][c] = s;
    __syncthreads();
    if (t < 128) atomicAdd(&sumbc[b * CCH + t], part[0][t] + part[1][t]);
}

// ---------------- fused MoE conv block (R23 core) + inline router + aux loss ----------------
__launch_bounds__(256, 4)
__global__ void moe_conv_kernel(const float* __restrict__ x, const bf16* __restrict__ xp,
                                const bf16* __restrict__ wt1r, const bf16* __restrict__ wt2r,
                                const float* __restrict__ b1, const float* __restrict__ b2,
                                const float* __restrict__ sumbc, const float* __restrict__ Wr,
                                const float* __restrict__ br,
                                float* __restrict__ out, float* __restrict__ total_out) {
    __shared__ __align__(16) bf16 Patch[2][108 * PPITCH];  // 2 x 8640 B
    __shared__ __align__(16) bf16 Ht[64 * HPITCH];         // 17408 B
    __shared__ double sh_lg[BB][EE];                       //  768 B (row 0 used by non-0 blocks)
    __shared__ double sh_pb[BB][EE];                       //  768 B
    __shared__ int    s_ei[2];
    __shared__ float  s_gv[2];

    const int wgid = blockIdx.x;
    const int work = (wgid & 7) * 288 + (wgid >> 3);
    const int b = work / 144;
    const int tile = work - b * 144;
    const int ty = tile / 6, tx = tile - ty * 6;
    const int y0 = ty * 4, x0 = tx * 16;

    const int t = threadIdx.x;
    const int lane = t & 63;
    const int w = t >> 6;
    const int lr = lane & 15;
    const int lh = lane >> 4;
    const int lq = lh * 4;

    const bf16* xpb = xp + (size_t)b * HP * HP * CCH;

    auto patch_dma = [&](int qn, int pb2) {
        bf16* base = &Patch[pb2][0];
        #pragma unroll
        for (int it = 0; it < 3; ++it) {
            int m = it * 256 + t;
            if (m < 540) {
                int rp = m / 5, sl = m - rp * 5;
                int g = (sl < 4) ? sl : 3;
                int py = rp / 18, px = rp - py * 18;
                gload16(xpb + ((size_t)(y0 + py) * HP + (x0 + px)) * CCH + qn * 32 + g * 8,
                        base + (it * 256 + w * 64) * 8);
            }
        }
    };
    auto loadA = [&](const bf16* chunk, v8bf* af) {
        #pragma unroll
        for (int i = 0; i < 2; ++i)
            af[i] = *reinterpret_cast<const v8bf*>(chunk + ((w * 2 + i) * 64 + lane) * 8);
    };

    const bf16* pL0 = &Patch[0][lr * PPITCH + lh * 8];
    const bf16* pL1 = &Patch[1][lr * PPITCH + lh * 8];
    const bf16* hL  = &Ht[lr * HPITCH + lh * 8];

    // ---- prologue: issue patch(q0) DMA, compute gates under it (f64, router-identical) ----
    patch_dma(0, 0);

    constexpr float rmn = 1.f / (HH * WW);
    if (work == 0) {
        if (t < BB * EE) {
            int bb = t / EE, e = t - (t / EE) * EE;
            double s = (double)br[e];
            for (int c = 0; c < CCH; ++c)
                s += (double)(sumbc[bb * CCH + c] * rmn) * (double)Wr[c * EE + e];
            if (s > 10.0) s = 10.0;
            if (s < -10.0) s = -10.0;
            sh_lg[bb][e] = s;
        }
    } else if (t < EE) {
        double s = (double)br[t];
        for (int c = 0; c < CCH; ++c)
            s += (double)(sumbc[b * CCH + c] * rmn) * (double)Wr[c * EE + t];
        if (s > 10.0) s = 10.0;
        if (s < -10.0) s = -10.0;
        sh_lg[0][t] = s;
    }
    __syncthreads();                      // publishes logits; also drains patch DMA
    {
        const int nrow = (work == 0) ? BB : 1;
        if (t < nrow) {
            double mx = sh_lg[t][0];
            for (int e = 1; e < EE; ++e) mx = fmax(mx, sh_lg[t][e]);
            double den = 0.0, p[EE];
            for (int e = 0; e < EE; ++e) { p[e] = exp(sh_lg[t][e] - mx); den += p[e]; }
            for (int e = 0; e < EE; ++e) {
                p[e] /= den;
                if (p[e] < 1e-6) p[e] = 1e-6;
                if (p[e] > 1.0)  p[e] = 1.0;
                sh_pb[t][e] = p[e];
            }
        }
    }
    __syncthreads();
    if (t == 0) {                         // top-2 + renorm for OUR b (row 0; work==0 -> b==0)
        const double* p = sh_pb[0];
        int a0 = 0;
        for (int e = 1; e < EE; ++e) if (p[e] > p[a0]) a0 = e;
        int a1 = (a0 == 0) ? 1 : 0;
        for (int e = 0; e < EE; ++e) if (e != a0 && p[e] > p[a1]) a1 = e;
        double s2 = p[a0] + p[a1] + 1e-8;
        s_ei[0] = a0; s_ei[1] = a1;
        s_gv[0] = (float)(p[a0] / s2);
        s_gv[1] = (float)(p[a1] / s2);
    }
    if (work == 0 && t == 64) {           // aux loss (one block, separate wave)
        double usage[EE] = {0, 0, 0, 0, 0, 0};
        double ent = 0.0;
        for (int bb = 0; bb < BB; ++bb) {
            double eb = 0.0;
            for (int e = 0; e < EE; ++e) {
                double pv = sh_pb[bb][e];
                usage[e] += pv;
                eb -= pv * log(pv + 1e-10);
            }
            ent += eb;
        }
        ent /= (double)BB;
        double lb = 0.0;
        for (int e = 0; e < EE; ++e) {
            double u = usage[e] / (double)BB - 1.0 / (double)EE;
            lb += u * u;
        }
        *total_out = (float)(lb * 5e-4 - ent * 1e-3);
    }
    __syncthreads();
    const int e0 = s_ei[0], e1 = s_ei[1];
    const float g0 = s_gv[0], g1 = s_gv[1];

    f32x4 accA[2][4], accB[2][4];
    #pragma unroll
    for (int i = 0; i < 2; ++i)
        #pragma unroll
        for (int j = 0; j < 4; ++j) {
            f32x4 z = {0.f, 0.f, 0.f, 0.f};
            accA[i][j] = z; accB[i][j] = z;
        }

#define DO_TAP(TAP, AC0, AC1, AN0, AN1)                                        \
    {                                                                          \
        if ((TAP) < 8) {                                                       \
            loadA(wb0 + ((TAP) + 1) * 4096, AN0);                              \
            loadA(wb1 + ((TAP) + 1) * 4096, AN1);                              \
        }                                                                      \
        v8bf bv[4];                                                            \
        const int ry_ = (TAP) / 3, sx_ = (TAP) % 3;                            \
        _Pragma("unroll")                                                      \
        for (int j = 0; j < 4; ++j)                                            \
            bv[j] = *reinterpret_cast<const v8bf*>(&pbL[((j + ry_) * 18 + sx_) * PPITCH]); \
        __builtin_amdgcn_s_setprio(1);                                         \
        _Pragma("unroll")                                                      \
        for (int i = 0; i < 2; ++i) {                                          \
            _Pragma("unroll")                                                  \
            for (int j = 0; j < 4; ++j) {                                      \
                accA[i][j] = __builtin_amdgcn_mfma_f32_16x16x32_bf16(AC0[i], bv[j], accA[i][j], 0, 0, 0); \
                accB[i][j] = __builtin_amdgcn_mfma_f32_16x16x32_bf16(AC1[i], bv[j], accB[i][j], 0, 0, 0); \
            }                                                                  \
        }                                                                      \
        __builtin_amdgcn_s_setprio(0);                                         \
    }

    #pragma unroll 1
    for (int q = 0; q < 4; ++q) {
        const bf16* pbL = (q & 1) ? pL1 : pL0;
        const bf16* wb0 = wt1r + ((size_t)(e0 * 36 + q * 9)) * 4096;
        const bf16* wb1 = wt1r + ((size_t)(e1 * 36 + q * 9)) * 4096;

        v8bf P0[2], P1[2], Q0[2], Q1[2];
        loadA(wb0, P0);
        loadA(wb1, P1);
        if (q < 3) patch_dma(q + 1, (q + 1) & 1);

        DO_TAP(0, P0, P1, Q0, Q1)
        DO_TAP(1, Q0, Q1, P0, P1)
        DO_TAP(2, P0, P1, Q0, Q1)
        DO_TAP(3, Q0, Q1, P0, P1)
        DO_TAP(4, P0, P1, Q0, Q1)
        DO_TAP(5, Q0, Q1, P0, P1)
        DO_TAP(6, P0, P1, Q0, Q1)
        DO_TAP(7, Q0, Q1, P0, P1)
        DO_TAP(8, P0, P1, Q0, Q1)

        if (q < 3) {
            WAITVM0;
            __builtin_amdgcn_s_barrier();
        }
    }
#undef DO_TAP

    #pragma unroll
    for (int ek = 0; ek < 2; ++ek) {
        const int e = ek ? e1 : e0;
        const float g = ek ? g1 : g0;
        const float* b1e = b1 + e * CCH;
        #pragma unroll
        for (int i = 0; i < 2; ++i) {
            const int cb = w * 32 + i * 16 + lq;
            float bias[4];
            #pragma unroll
            for (int q2 = 0; q2 < 4; ++q2) bias[q2] = b1e[cb + q2];
            #pragma unroll
            for (int j = 0; j < 4; ++j) {
                const int pos = j * 16 + lr;
                f32x4 src = ek ? accB[i][j] : accA[i][j];
                if (ek == 0) { f32x4 z = {0.f,0.f,0.f,0.f}; accA[i][j] = z; }
                bf16 hv[4];
                #pragma unroll
                for (int q2 = 0; q2 < 4; ++q2) {
                    float v = src[q2] + bias[q2];
                    float en = __expf(-1.5957691216057308f * v * fmaf(0.044715f, v * v, 1.0f));
                    float s  = __builtin_amdgcn_rcpf(1.0f + en);
                    hv[q2] = to_bf16(g * v * s);
                }
                *reinterpret_cast<uint2*>(&Ht[pos * HPITCH + cb]) =
                    *reinterpret_cast<uint2*>(hv);
            }
        }
        __syncthreads();

        const bf16* w2b = wt2r + (size_t)e * 4 * 4096;
        v8bf afc[2], afn[2];
        loadA(w2b, afc);
        #pragma unroll
        for (int kc = 0; kc < 4; ++kc) {
            if (kc < 3) loadA(w2b + (kc + 1) * 4096, afn);
            v8bf bv[4];
            #pragma unroll
            for (int j = 0; j < 4; ++j)
                bv[j] = *reinterpret_cast<const v8bf*>(&hL[j * 16 * HPITCH + kc * 32]);
            __builtin_amdgcn_s_setprio(1);
            #pragma unroll
            for (int i = 0; i < 2; ++i)
                #pragma unroll
                for (int j = 0; j < 4; ++j)
                    accA[i][j] = __builtin_amdgcn_mfma_f32_16x16x32_bf16(afc[i], bv[j], accA[i][j], 0, 0, 0);
            __builtin_amdgcn_s_setprio(0);
            if (kc < 3) {
                afc[0] = afn[0];
                afc[1] = afn[1];
            }
        }
        if (ek == 0) __syncthreads();
    }

    // ---- epilogue: out = accA + (g0*b2[e0] + g1*b2[e1]) + (g0+g1)*x ----
    const float gsum = g0 + g1;
    #pragma unroll
    for (int i = 0; i < 2; ++i) {
        const int cb = w * 32 + i * 16 + lq;
        float bs[4];
        #pragma unroll
        for (int q2 = 0; q2 < 4; ++q2)
            bs[q2] = g0 * b2[e0 * CCH + cb + q2] + g1 * b2[e1 * CCH + cb + q2];
        #pragma unroll
        for (int j = 0; j < 4; ++j) {
            const int pos = j * 16 + lr;
            const int yy = y0 + (pos >> 4), xx = x0 + (pos & 15);
            #pragma unroll
            for (int q2 = 0; q2 < 4; ++q2) {
                size_t gi = (((size_t)b * CCH + cb + q2) * HH + yy) * WW + xx;
                out[gi] = accA[i][j][q2] + bs[q2] + gsum * x[gi];
            }
        }
    }
}

extern "C" void kernel_launch(void* const* d_in, const int* in_sizes, int n_in,
                              void* d_out, int out_size, void* d_ws, size_t ws_size,
                              hipStream_t stream) {
    const float* x  = (const float*)d_in[0];
    const float* Wr = (const float*)d_in[1];
    const float* br = (const float*)d_in[2];
    const float* W1 = (const float*)d_in[3];
    const float* b1 = (const float*)d_in[4];
    const float* W2 = (const float*)d_in[5];
    const float* b2 = (const float*)d_in[6];
    float* out = (float*)d_out;

    char* ws = (char*)d_ws;
    bf16* xp    = (bf16*)ws;
    bf16* wt1r  = (bf16*)(ws + XP_BYTES);
    bf16* wt2r  = (bf16*)(ws + XP_BYTES + WT1R_BYTES);
    float* sumbc = (float*)(ws + XP_BYTES + WT1R_BYTES + WT2R_BYTES);
    float* total = out + (size_t)BB * CCH * HH * WW;

    hipMemsetAsync(sumbc, 0, (size_t)BB * CCH * 4, stream);
    padwt_kernel<<<PAD_BLOCKS + WT_BLOCKS, 256, 0, stream>>>(x, xp, sumbc, W1, W2, wt1r, wt2r);
    moe_conv_kernel<<<2304, 256, 0, stream>>>(x, xp, wt1r, wt2r, b1, b2, sumbc, Wr, br, out, total);
}

// Round 25
// 139.277 us; speedup vs baseline: 1.2428x; 1.0069x over previous
//
#include <hip/hip_runtime.h>
#include <hip/hip_bf16.h>

typedef __bf16 bf16;
typedef __bf16 v8bf __attribute__((ext_vector_type(8)));
typedef float f32x4 __attribute__((ext_vector_type(4)));

#define BB 16
#define CCH 128
#define HH 96
#define WW 96
#define EE 6
#define HP 98

#define PPITCH 40      // Patch row pitch in bf16 elems (80 B = 32 data + 16 pad)
#define HPITCH 136     // Ht row pitch in bf16 elems (272 B = 256 data + 16 pad)

static constexpr size_t XP_ELEMS   = (size_t)BB * HP * HP * CCH;
static constexpr size_t WT1R_ELEMS = (size_t)EE * 36 * 4096;
static constexpr size_t WT2R_ELEMS = (size_t)EE * 4 * 4096;
static constexpr size_t XP_BYTES   = XP_ELEMS * 2;
static constexpr size_t WT1R_BYTES = WT1R_ELEMS * 2;
static constexpr size_t WT2R_BYTES = WT2R_ELEMS * 2;

static constexpr int PAD_BLOCKS = HH * BB;                                      // 1536
static constexpr int WT_BLOCKS  = (int)((WT1R_ELEMS + WT2R_ELEMS + 255) / 256); // 874

__device__ inline bf16 to_bf16(float f) { return (bf16)f; }

__device__ __forceinline__ void gload16(const bf16* gsrc, bf16* ldst_wave_uniform) {
    __builtin_amdgcn_global_load_lds(
        (const __attribute__((address_space(1))) unsigned int*)gsrc,
        (__attribute__((address_space(3))) unsigned int*)ldst_wave_uniform, 16, 0, 0);
}

#define WAITVM0 asm volatile("s_waitcnt vmcnt(0)" ::: "memory")

// ---------------- fused: pad (+halo, +channel sums) | weight transform ----------------
__global__ void padwt_kernel(const float* __restrict__ x, bf16* __restrict__ xp,
                             float* __restrict__ sumbc,
                             const float* __restrict__ w1, const float* __restrict__ w2,
                             bf16* __restrict__ wt1r, bf16* __restrict__ wt2r) {
    const int blk = blockIdx.x;
    const int t = threadIdx.x;
    if (blk >= PAD_BLOCKS) {
        // ---- weight transform path (frag-contiguous, verified R10) ----
        const int idx = (blk - PAD_BLOCKS) * 256 + t;
        const int W1N = (int)WT1R_ELEMS;
        if (idx < W1N) {
            int o = idx & 4095;
            int lo = o & 7;
            int l8 = (o >> 3) & 63;
            int rblk = o >> 9;
            int lh2 = l8 >> 4, lr2 = l8 & 15;
            int row = rblk * 16 + lr2;
            int kk = lh2 * 8 + lo;
            int cg = idx >> 12;
            int e = cg / 36, c = cg - e * 36;
            int q = c / 9, tap = c - q * 9;
            int cin = q * 32 + kk;
            wt1r[idx] = to_bf16(w1[((size_t)(e * CCH + row) * CCH + cin) * 9 + tap]);
        } else if (idx < W1N + (int)WT2R_ELEMS) {
            int j2 = idx - W1N;
            int o = j2 & 4095;
            int lo = o & 7;
            int l8 = (o >> 3) & 63;
            int rblk = o >> 9;
            int lh2 = l8 >> 4, lr2 = l8 & 15;
            int row = rblk * 16 + lr2;
            int kk = lh2 * 8 + lo;
            int cg = j2 >> 12;
            int e = cg >> 2, kc = cg & 3;
            int cin = kc * 32 + kk;
            wt2r[j2] = to_bf16(w2[(size_t)(e * CCH + row) * CCH + cin]);
        }
        return;
    }
    // ---- pad path (R23 vectorized body) ----
    __shared__ float tile[WW][CCH + 2];
    __shared__ float part[2][CCH];
    const int y = blk % HH;
    const int b = blk / HH;
    const float* src = x + (size_t)b * CCH * HH * WW + (size_t)y * WW;
    bf16* xpb = xp + (size_t)b * HP * HP * CCH;
    for (int i = t; i < CCH * (WW / 4); i += 256) {
        int c = i / (WW / 4);
        int xq = i - c * (WW / 4);
        float4 v = *reinterpret_cast<const float4*>(src + (size_t)c * HH * WW + xq * 4);
        tile[xq * 4 + 0][c] = v.x;
        tile[xq * 4 + 1][c] = v.y;
        tile[xq * 4 + 2][c] = v.z;
        tile[xq * 4 + 3][c] = v.w;
    }
    uint4 z; z.x = z.y = z.z = z.w = 0u;
    if (t < 32) {
        int col = t >> 4, gci = t & 15;
        int xx = col ? 97 : 0;
        *reinterpret_cast<uint4*>(xpb + (((size_t)(y + 1)) * HP + xx) * CCH + gci * 8) = z;
    }
    if (y == 0)
        for (int m = t; m < 98 * 16; m += 256) {
            int cell = m >> 4, gci = m & 15;
            *reinterpret_cast<uint4*>(xpb + ((size_t)cell) * CCH + gci * 8) = z;
        }
    if (y == HH - 1)
        for (int m = t; m < 98 * 16; m += 256) {
            int cell = m >> 4, gci = m & 15;
            *reinterpret_cast<uint4*>(xpb + ((size_t)97 * HP + cell) * CCH + gci * 8) = z;
        }
    __syncthreads();
    bf16* dst = xpb + (((size_t)(y + 1)) * HP + 1) * CCH;
    for (int j = t; j < WW * 16; j += 256) {
        int xx = j >> 4;
        int c8 = (j & 15) * 8;
        bf16 pr[8];
        #pragma unroll
        for (int k = 0; k < 8; ++k) pr[k] = to_bf16(tile[xx][c8 + k]);
        *reinterpret_cast<uint4*>(&dst[(size_t)xx * CCH + c8]) = *reinterpret_cast<uint4*>(pr);
    }
    const int c = t & 127, half = t >> 7;
    float s = 0.f;
    for (int xx = half * 48; xx < half * 48 + 48; ++xx) s += tile[xx][c];
    part[half][c] = s;
    __syncthreads();
    if (t < 128) atomicAdd(&sumbc[b * CCH + t], part[0][t] + part[1][t]);
}

// ---------------- fused MoE conv block (R23 core) + PARALLEL inline router + aux loss ----------------
__launch_bounds__(256, 4)
__global__ void moe_conv_kernel(const float* __restrict__ x, const bf16* __restrict__ xp,
                                const bf16* __restrict__ wt1r, const bf16* __restrict__ wt2r,
                                const float* __restrict__ b1, const float* __restrict__ b2,
                                const float* __restrict__ sumbc, const float* __restrict__ Wr,
                                const float* __restrict__ br,
                                float* __restrict__ out, float* __restrict__ total_out) {
    __shared__ __align__(16) bf16 Patch[2][108 * PPITCH];  // 2 x 8640 B
    __shared__ __align__(16) bf16 Ht[64 * HPITCH];         // 17408 B
    __shared__ double sh_red[2][EE];                       // wave partials
    __shared__ double sh_lg[BB][EE];
    __shared__ double sh_pb[BB][EE];
    __shared__ int    s_ei[2];
    __shared__ float  s_gv[2];

    const int wgid = blockIdx.x;
    const int work = (wgid & 7) * 288 + (wgid >> 3);
    const int b = work / 144;
    const int tile = work - b * 144;
    const int ty = tile / 6, tx = tile - ty * 6;
    const int y0 = ty * 4, x0 = tx * 16;

    const int t = threadIdx.x;
    const int lane = t & 63;
    const int w = t >> 6;
    const int lr = lane & 15;
    const int lh = lane >> 4;
    const int lq = lh * 4;

    const bf16* xpb = xp + (size_t)b * HP * HP * CCH;

    auto patch_dma = [&](int qn, int pb2) {
        bf16* base = &Patch[pb2][0];
        #pragma unroll
        for (int it = 0; it < 3; ++it) {
            int m = it * 256 + t;
            if (m < 540) {
                int rp = m / 5, sl = m - rp * 5;
                int g = (sl < 4) ? sl : 3;
                int py = rp / 18, px = rp - py * 18;
                gload16(xpb + ((size_t)(y0 + py) * HP + (x0 + px)) * CCH + qn * 32 + g * 8,
                        base + (it * 256 + w * 64) * 8);
            }
        }
    };
    auto loadA = [&](const bf16* chunk, v8bf* af) {
        #pragma unroll
        for (int i = 0; i < 2; ++i)
            af[i] = *reinterpret_cast<const v8bf*>(chunk + ((w * 2 + i) * 64 + lane) * 8);
    };

    const bf16* pL0 = &Patch[0][lr * PPITCH + lh * 8];
    const bf16* pL1 = &Patch[1][lr * PPITCH + lh * 8];
    const bf16* hL  = &Ht[lr * HPITCH + lh * 8];

    // ---- prologue: issue patch(q0) DMA; compute gates under it (parallel f64 dot) ----
    patch_dma(0, 0);

    constexpr float rmn = 1.f / (HH * WW);
    const int nb = (work == 0) ? BB : 1;
    for (int it = 0; it < nb; ++it) {
        const int bb = (work == 0) ? it : b;
        double ps[EE];
        if (t < 128) {
            double xv = (double)(sumbc[bb * CCH + t] * rmn);
            #pragma unroll
            for (int e = 0; e < EE; ++e) ps[e] = xv * (double)Wr[t * EE + e];
        } else {
            #pragma unroll
            for (int e = 0; e < EE; ++e) ps[e] = 0.0;
        }
        #pragma unroll
        for (int e = 0; e < EE; ++e) {
            double s = ps[e];
            for (int off = 32; off; off >>= 1) s += __shfl_down(s, off);
            ps[e] = s;
        }
        if (lane == 0 && t < 128) {
            #pragma unroll
            for (int e = 0; e < EE; ++e) sh_red[w][e] = ps[e];
        }
        __syncthreads();
        if (t < EE) {
            double s = (double)br[t] + sh_red[0][t] + sh_red[1][t];
            if (s > 10.0) s = 10.0;
            if (s < -10.0) s = -10.0;
            sh_lg[(work == 0) ? it : 0][t] = s;
        }
        __syncthreads();
    }
    {
        const int nrow = (work == 0) ? BB : 1;
        if (t < nrow) {
            double mx = sh_lg[t][0];
            for (int e = 1; e < EE; ++e) mx = fmax(mx, sh_lg[t][e]);
            double den = 0.0, p[EE];
            for (int e = 0; e < EE; ++e) { p[e] = exp(sh_lg[t][e] - mx); den += p[e]; }
            for (int e = 0; e < EE; ++e) {
                p[e] /= den;
                if (p[e] < 1e-6) p[e] = 1e-6;
                if (p[e] > 1.0)  p[e] = 1.0;
                sh_pb[t][e] = p[e];
            }
        }
    }
    __syncthreads();
    if (t == 0) {                         // top-2 + renorm for OUR b (row 0; work==0 -> b==0)
        const double* p = sh_pb[0];
        int a0 = 0;
        for (int e = 1; e < EE; ++e) if (p[e] > p[a0]) a0 = e;
        int a1 = (a0 == 0) ? 1 : 0;
        for (int e = 0; e < EE; ++e) if (e != a0 && p[e] > p[a1]) a1 = e;
        double s2 = p[a0] + p[a1] + 1e-8;
        s_ei[0] = a0; s_ei[1] = a1;
        s_gv[0] = (float)(p[a0] / s2);
        s_gv[1] = (float)(p[a1] / s2);
    }
    if (work == 0 && t == 64) {           // aux loss (one block, separate wave)
        double usage[EE] = {0, 0, 0, 0, 0, 0};
        double ent = 0.0;
        for (int bb = 0; bb < BB; ++bb) {
            double eb = 0.0;
            for (int e = 0; e < EE; ++e) {
                double pv = sh_pb[bb][e];
                usage[e] += pv;
                eb -= pv * log(pv + 1e-10);
            }
            ent += eb;
        }
        ent /= (double)BB;
        double lb = 0.0;
        for (int e = 0; e < EE; ++e) {
            double u = usage[e] / (double)BB - 1.0 / (double)EE;
            lb += u * u;
        }
        *total_out = (float)(lb * 5e-4 - ent * 1e-3);
    }
    __syncthreads();
    const int e0 = s_ei[0], e1 = s_ei[1];
    const float g0 = s_gv[0], g1 = s_gv[1];

    f32x4 accA[2][4], accB[2][4];
    #pragma unroll
    for (int i = 0; i < 2; ++i)
        #pragma unroll
        for (int j = 0; j < 4; ++j) {
            f32x4 z = {0.f, 0.f, 0.f, 0.f};
            accA[i][j] = z; accB[i][j] = z;
        }

#define DO_TAP(TAP, AC0, AC1, AN0, AN1)                                        \
    {                                                                          \
        if ((TAP) < 8) {                                                       \
            loadA(wb0 + ((TAP) + 1) * 4096, AN0);                              \
            loadA(wb1 + ((TAP) + 1) * 4096, AN1);                              \
        }                                                                      \
        v8bf bv[4];                                                            \
        const int ry_ = (TAP) / 3, sx_ = (TAP) % 3;                            \
        _Pragma("unroll")                                                      \
        for (int j = 0; j < 4; ++j)                                            \
            bv[j] = *reinterpret_cast<const v8bf*>(&pbL[((j + ry_) * 18 + sx_) * PPITCH]); \
        __builtin_amdgcn_s_setprio(1);                                         \
        _Pragma("unroll")                                                      \
        for (int i = 0; i < 2; ++i) {                                          \
            _Pragma("unroll")                                                  \
            for (int j = 0; j < 4; ++j) {                                      \
                accA[i][j] = __builtin_amdgcn_mfma_f32_16x16x32_bf16(AC0[i], bv[j], accA[i][j], 0, 0, 0); \
                accB[i][j] = __builtin_amdgcn_mfma_f32_16x16x32_bf16(AC1[i], bv[j], accB[i][j], 0, 0, 0); \
            }                                                                  \
        }                                                                      \
        __builtin_amdgcn_s_setprio(0);                                         \
    }

    #pragma unroll 1
    for (int q = 0; q < 4; ++q) {
        const bf16* pbL = (q & 1) ? pL1 : pL0;
        const bf16* wb0 = wt1r + ((size_t)(e0 * 36 + q * 9)) * 4096;
        const bf16* wb1 = wt1r + ((size_t)(e1 * 36 + q * 9)) * 4096;

        v8bf P0[2], P1[2], Q0[2], Q1[2];
        loadA(wb0, P0);
        loadA(wb1, P1);
        if (q < 3) patch_dma(q + 1, (q + 1) & 1);

        DO_TAP(0, P0, P1, Q0, Q1)
        DO_TAP(1, Q0, Q1, P0, P1)
        DO_TAP(2, P0, P1, Q0, Q1)
        DO_TAP(3, Q0, Q1, P0, P1)
        DO_TAP(4, P0, P1, Q0, Q1)
        DO_TAP(5, Q0, Q1, P0, P1)
        DO_TAP(6, P0, P1, Q0, Q1)
        DO_TAP(7, Q0, Q1, P0, P1)
        DO_TAP(8, P0, P1, Q0, Q1)

        if (q < 3) {
            WAITVM0;
            __builtin_amdgcn_s_barrier();
        }
    }
#undef DO_TAP

    #pragma unroll
    for (int ek = 0; ek < 2; ++ek) {
        const int e = ek ? e1 : e0;
        const float g = ek ? g1 : g0;
        const float* b1e = b1 + e * CCH;
        #pragma unroll
        for (int i = 0; i < 2; ++i) {
            const int cb = w * 32 + i * 16 + lq;
            float bias[4];
            #pragma unroll
            for (int q2 = 0; q2 < 4; ++q2) bias[q2] = b1e[cb + q2];
            #pragma unroll
            for (int j = 0; j < 4; ++j) {
                const int pos = j * 16 + lr;
                f32x4 src = ek ? accB[i][j] : accA[i][j];
                if (ek == 0) { f32x4 z = {0.f,0.f,0.f,0.f}; accA[i][j] = z; }
                bf16 hv[4];
                #pragma unroll
                for (int q2 = 0; q2 < 4; ++q2) {
                    float v = src[q2] + bias[q2];
                    float en = __expf(-1.5957691216057308f * v * fmaf(0.044715f, v * v, 1.0f));
                    float s  = __builtin_amdgcn_rcpf(1.0f + en);
                    hv[q2] = to_bf16(g * v * s);
                }
                *reinterpret_cast<uint2*>(&Ht[pos * HPITCH + cb]) =
                    *reinterpret_cast<uint2*>(hv);
            }
        }
        __syncthreads();

        const bf16* w2b = wt2r + (size_t)e * 4 * 4096;
        v8bf afc[2], afn[2];
        loadA(w2b, afc);
        #pragma unroll
        for (int kc = 0; kc < 4; ++kc) {
            if (kc < 3) loadA(w2b + (kc + 1) * 4096, afn);
            v8bf bv[4];
            #pragma unroll
            for (int j = 0; j < 4; ++j)
                bv[j] = *reinterpret_cast<const v8bf*>(&hL[j * 16 * HPITCH + kc * 32]);
            __builtin_amdgcn_s_setprio(1);
            #pragma unroll
            for (int i = 0; i < 2; ++i)
                #pragma unroll
                for (int j = 0; j < 4; ++j)
                    accA[i][j] = __builtin_amdgcn_mfma_f32_16x16x32_bf16(afc[i], bv[j], accA[i][j], 0, 0, 0);
            __builtin_amdgcn_s_setprio(0);
            if (kc < 3) {
                afc[0] = afn[0];
                afc[1] = afn[1];
            }
        }
        if (ek == 0) __syncthreads();
    }

    // ---- epilogue: out = accA + (g0*b2[e0] + g1*b2[e1]) + (g0+g1)*x ----
    const float gsum = g0 + g1;
    #pragma unroll
    for (int i = 0; i < 2; ++i) {
        const int cb = w * 32 + i * 16 + lq;
        float bs[4];
        #pragma unroll
        for (int q2 = 0; q2 < 4; ++q2)
            bs[q2] = g0 * b2[e0 * CCH + cb + q2] + g1 * b2[e1 * CCH + cb + q2];
        #pragma unroll
        for (int j = 0; j < 4; ++j) {
            const int pos = j * 16 + lr;
            const int yy = y0 + (pos >> 4), xx = x0 + (pos & 15);
            #pragma unroll
            for (int q2 = 0; q2 < 4; ++q2) {
                size_t gi = (((size_t)b * CCH + cb + q2) * HH + yy) * WW + xx;
                out[gi] = accA[i][j][q2] + bs[q2] + gsum * x[gi];
            }
        }
    }
}

extern "C" void kernel_launch(void* const* d_in, const int* in_sizes, int n_in,
                              void* d_out, int out_size, void* d_ws, size_t ws_size,
                              hipStream_t stream) {
    const float* x  = (const float*)d_in[0];
    const float* Wr = (const float*)d_in[1];
    const float* br = (const float*)d_in[2];
    const float* W1 = (const float*)d_in[3];
    const float* b1 = (const float*)d_in[4];
    const float* W2 = (const float*)d_in[5];
    const float* b2 = (const float*)d_in[6];
    float* out = (float*)d_out;

    char* ws = (char*)d_ws;
    bf16* xp    = (bf16*)ws;
    bf16* wt1r  = (bf16*)(ws + XP_BYTES);
    bf16* wt2r  = (bf16*)(ws + XP_BYTES + WT1R_BYTES);
    float* sumbc = (float*)(ws + XP_BYTES + WT1R_BYTES + WT2R_BYTES);
    float* total = out + (size_t)BB * CCH * HH * WW;

    hipMemsetAsync(sumbc, 0, (size_t)BB * CCH * 4, stream);
    padwt_kernel<<<PAD_BLOCKS + WT_BLOCKS, 256, 0, stream>>>(x, xp, sumbc, W1, W2, wt1r, wt2r);
    moe_conv_kernel<<<2304, 256, 0, stream>>>(x, xp, wt1r, wt2r, b1, b2, sumbc, Wr, br, out, total);
}